// Round 6
// baseline (25.079 us; speedup 1.0000x reference)
//
#include <hip/hip_runtime.h>

// ---------------------------------------------------------------------------
// Quantum conv2d, packed-fp32, SGPR-gate edition.
// Gate matrices are wave-uniform -> precomputed into global memory (d_ws) by
// a tiny prep kernel, then read via uniform loads => s_load into SGPRs.
// VOP3P pk_fma reads coefficients straight from SGPR pairs: no VGPR pressure,
// no LDS/vector loads in the gate loop. State f2[16] stays in VGPRs.
// ---------------------------------------------------------------------------

typedef float f2 __attribute__((ext_vector_type(2)));

__device__ __forceinline__ f2 pkfma(f2 a, f2 b, f2 c) {
    return __builtin_elementwise_fma(a, b, c);
}
__device__ __forceinline__ f2 swap2(f2 v) {
    return __builtin_shufflevector(v, v, 1, 0);
}

struct GateM { f2 m00rr, m00ni, m01rr, m01ni, m10rr, m10ni, m11rr, m11ni; };

__device__ __forceinline__ GateM load_gate(const float* gp) {
    const float4* p = (const float4*)gp;
    const float4 e0 = p[0], e1 = p[1], e2 = p[2], e3 = p[3];
    GateM G;
    G.m00rr = f2{e0.x, e0.y}; G.m00ni = f2{e0.z, e0.w};
    G.m01rr = f2{e1.x, e1.y}; G.m01ni = f2{e1.z, e1.w};
    G.m10rr = f2{e2.x, e2.y}; G.m10ni = f2{e2.z, e2.w};
    G.m11rr = f2{e3.x, e3.y}; G.m11ni = f2{e3.z, e3.w};
    return G;
}

template<int STRIDE>
__device__ __forceinline__ void apply_gate(f2* s, const GateM G) {
    #pragma unroll
    for (int m0 = 0; m0 < 16; ++m0) {
        if (m0 & STRIDE) continue;
        const int m1 = m0 | STRIDE;
        const f2 a = s[m0], b = s[m1];
        const f2 as = swap2(a), bs = swap2(b);
        f2 o0 = G.m00rr * a;
        o0 = pkfma(G.m00ni, as, o0);
        o0 = pkfma(G.m01rr, b,  o0);
        o0 = pkfma(G.m01ni, bs, o0);
        f2 o1 = G.m10rr * a;
        o1 = pkfma(G.m10ni, as, o1);
        o1 = pkfma(G.m11rr, b,  o1);
        o1 = pkfma(G.m11ni, bs, o1);
        s[m0] = o0; s[m1] = o1;
    }
}

template<int BC, int BT>
__device__ __forceinline__ void apply_cnot(f2* s) {
    #pragma unroll
    for (int m = 0; m < 16; ++m) {
        if ((m & BC) && !(m & BT)) {
            const int m2 = m | BT;
            const f2 t = s[m]; s[m] = s[m2]; s[m2] = t;
        }
    }
}

struct Node { f2 cc, ss, ns; };

// Multiplexed-RY node from un-normalized child sums (scale cancels).
__device__ __forceinline__ Node node_cs(float lo, float hi) {
    const float den = lo + hi;
    const bool ok = den > 1e-30f;
    const float rs = __builtin_amdgcn_rsqf(fmaxf(den, 1e-37f));
    const float c = ok ? __builtin_amdgcn_sqrtf(lo) * rs : 1.0f;
    const float s = ok ? __builtin_amdgcn_sqrtf(hi) * rs : 0.0f;
    return Node{f2{c, c}, f2{s, s}, f2{-s, -s}};
}

template<int I0, int I1>
__device__ __forceinline__ void rot_pair(f2* s, const Node& n) {
    const f2 a = s[I0], b = s[I1];
    s[I0] = pkfma(n.cc, a, n.ns * b);
    s[I1] = pkfma(n.ss, a, n.cc * b);
}

__device__ __forceinline__ void cascade(f2* s, const float* Q) {
    const float s01 = Q[0]+Q[1], s23 = Q[2]+Q[3];
    const float s45 = Q[4]+Q[5], s67 = Q[6]+Q[7];
    const float s03 = s01+s23, s47 = s45+s67, s07 = s03+s47;
    const Node n0  = node_cs(s07,  Q[8]);   // t=0
    const Node n1  = node_cs(s03,  s47);    // t=1 b=0 (b=1 identity)
    const Node n2a = node_cs(s01,  s23);    // t=2 b=0
    const Node n2b = node_cs(s45,  s67);    // t=2 b=1 (b=2,3 identity)
    const Node n3a = node_cs(Q[0], Q[1]);   // t=3 b=0
    const Node n3b = node_cs(Q[2], Q[3]);   // t=3 b=1
    const Node n3c = node_cs(Q[4], Q[5]);   // t=3 b=2
    const Node n3d = node_cs(Q[6], Q[7]);   // t=3 b=3 (b=4..7 identity)

    rot_pair<0, 8>(s, n0);  rot_pair<1, 9>(s, n0);
    rot_pair<2,10>(s, n0);  rot_pair<3,11>(s, n0);
    rot_pair<4,12>(s, n0);  rot_pair<5,13>(s, n0);
    rot_pair<6,14>(s, n0);  rot_pair<7,15>(s, n0);
    rot_pair<0, 4>(s, n1);  rot_pair<1, 5>(s, n1);
    rot_pair<2, 6>(s, n1);  rot_pair<3, 7>(s, n1);
    rot_pair<0, 2>(s, n2a); rot_pair<1, 3>(s, n2a);
    rot_pair<4, 6>(s, n2b); rot_pair<5, 7>(s, n2b);
    rot_pair<0, 1>(s, n3a); rot_pair<2, 3>(s, n3b);
    rot_pair<4, 5>(s, n3c); rot_pair<6, 7>(s, n3d);
}

// --- prep kernel: pack the 32 Rot matrices into global memory (d_ws) ---
__global__ void build_gates(const float* __restrict__ wts,
                            float* __restrict__ gmat) {
    const int tid = threadIdx.x;
    if (tid >= 32) return;
    const float phi   = wts[tid*3 + 0];
    const float theta = wts[tid*3 + 1];
    const float omega = wts[tid*3 + 2];
    float st, ct; __sincosf(0.5f * theta,         &st, &ct);
    float sA, cA; __sincosf(0.5f * (phi + omega), &sA, &cA);
    float sB, cB; __sincosf(0.5f * (phi - omega), &sB, &cB);
    float* g = gmat + tid * 16;
    // entry: {re, re, -im, im}
    g[0]  =  cA*ct; g[1]  =  cA*ct; g[2]  =  sA*ct; g[3]  = -sA*ct; // m00
    g[4]  = -cB*st; g[5]  = -cB*st; g[6]  =  sB*st; g[7]  = -sB*st; // m01
    g[8]  =  cB*st; g[9]  =  cB*st; g[10] =  sB*st; g[11] = -sB*st; // m10
    g[12] =  cA*ct; g[13] =  cA*ct; g[14] = -sA*ct; g[15] =  sA*ct; // m11
}

__global__ __launch_bounds__(256) void qconv_kernel(
        const float* __restrict__ x,     // (32, 4, 64, 64)
        const float* __restrict__ gmat,  // (32, 16) packed gates, uniform
        float* __restrict__ out) {       // (32, 16, 64, 64)
    __shared__ float tile[6 * 4 * 64];   // 6 KB: rows y0-1..y0+4, 4 channels

    const int tid = threadIdx.x;
    const int blk = blockIdx.x;
    const int b  = blk >> 4;             // image
    const int y0 = (blk & 15) << 2;      // first of 4 rows

    // --- stage input tile (coalesced), pad rows with 0.01 ---
    const float* xb = x + (size_t)b * 16384;
    #pragma unroll
    for (int i = 0; i < 6; ++i) {
        const int e = tid + i * 256;          // [r][ch][col]
        const int r = e >> 8, ch = (e >> 6) & 3, col = e & 63;
        const int gy = y0 - 1 + r;
        float v = 0.01f;
        if ((unsigned)gy < 64u) v = xb[ch * 4096 + gy * 64 + col];
        tile[e] = v;
    }
    __syncthreads();

    const int ly = tid >> 6, xc = tid & 63;
    const int colm = min(max(xc - 1, 0), 63);   // clamped col for dx=0
    const int colp = min(xc + 1, 63);           // clamped col for dx=2
    const bool inm = xc > 0, inp = xc < 63;

    f2 s[16];
    #pragma unroll
    for (int i = 0; i < 16; ++i) s[i] = f2{0.0f, 0.0f};
    s[0] = f2{1.0f, 0.0f};

    // --- 4 channels, rolled loop; gate coefficients come from SGPRs ---
    #pragma unroll 1
    for (int ic = 0; ic < 4; ++ic) {
        // squared 3x3 patch from LDS tile [6][4][64]
        float q[9];
        #pragma unroll
        for (int dy = 0; dy < 3; ++dy) {
            const float* row = tile + ((ly + dy) * 4 + ic) * 64;
            float vm = row[colm]; vm = inm ? vm : 0.01f;
            float v0 = row[xc];
            float vp = row[colp]; vp = inp ? vp : 0.01f;
            q[dy*3 + 0] = vm * vm;
            q[dy*3 + 1] = v0 * v0;
            q[dy*3 + 2] = vp * vp;
        }

        cascade(s, q);

        const float* cb = gmat + ic * 128;   // uniform address -> s_load
        apply_gate<8>(s, load_gate(cb + 0*16));
        apply_gate<4>(s, load_gate(cb + 1*16));
        apply_gate<2>(s, load_gate(cb + 2*16));
        apply_gate<1>(s, load_gate(cb + 3*16));
        apply_cnot<8, 4>(s); apply_cnot<4, 2>(s);
        apply_cnot<2, 1>(s); apply_cnot<1, 8>(s);
        apply_gate<8>(s, load_gate(cb + 4*16));
        apply_gate<4>(s, load_gate(cb + 5*16));
        apply_gate<2>(s, load_gate(cb + 6*16));
        apply_gate<1>(s, load_gate(cb + 7*16));
        apply_cnot<8, 2>(s); apply_cnot<4, 1>(s);
        apply_cnot<2, 8>(s); apply_cnot<1, 4>(s);
    }

    // --- probabilities -> clipped output, (b, 16, 64, 64) ---
    float* ob = out + (size_t)b * (16 * 4096) + (y0 + ly) * 64 + xc;
    #pragma unroll
    for (int m = 0; m < 16; ++m) {
        const float p = s[m].x * s[m].x + s[m].y * s[m].y;
        ob[m * 4096] = fminf(p * 8.0f, 1.0f);
    }
}

extern "C" void kernel_launch(void* const* d_in, const int* in_sizes, int n_in,
                              void* d_out, int out_size, void* d_ws, size_t ws_size,
                              hipStream_t stream) {
    const float* x   = (const float*)d_in[0];
    const float* wts = (const float*)d_in[1];
    float* out  = (float*)d_out;
    float* gmat = (float*)d_ws;          // 512 floats, rewritten every call
    build_gates<<<1, 64, 0, stream>>>(wts, gmat);
    qconv_kernel<<<512, 256, 0, stream>>>(x, gmat, out);
}

// Round 7
// 19.438 us; speedup vs baseline: 1.2902x; 1.2902x over previous
//
#include <hip/hip_runtime.h>

// ---------------------------------------------------------------------------
// Quantum conv2d, packed-fp32, asm-pinned register prefetch.
// The register allocator (tuned for occupancy we can't use: grid gives only
// 2 waves/SIMD) keeps sinking prefetched LDS loads back to point-of-use,
// serializing ~40 x ~120cy LDS latency per thread. volatile-asm "+v" pins
// force batched issue: per channel, 9 patch reads + 32 gate reads go out
// back-to-back, cascade overlaps the gate loads, one wait each.
// ---------------------------------------------------------------------------

typedef float f2 __attribute__((ext_vector_type(2)));

__device__ __forceinline__ f2 pkfma(f2 a, f2 b, f2 c) {
    return __builtin_elementwise_fma(a, b, c);
}
__device__ __forceinline__ f2 swap2(f2 v) {
    return __builtin_shufflevector(v, v, 1, 0);
}
__device__ __forceinline__ void pin2(f2& v)  { asm volatile("" : "+v"(v)); }
__device__ __forceinline__ void pinf(float& v) { asm volatile("" : "+v"(v)); }

struct GateM { f2 m00rr, m00ni, m01rr, m01ni, m10rr, m10ni, m11rr, m11ni; };

__device__ __forceinline__ GateM load_gate(const float* gp) {
    const float4* p = (const float4*)gp;
    const float4 e0 = p[0], e1 = p[1], e2 = p[2], e3 = p[3];
    GateM G;
    G.m00rr = f2{e0.x, e0.y}; G.m00ni = f2{e0.z, e0.w};
    G.m01rr = f2{e1.x, e1.y}; G.m01ni = f2{e1.z, e1.w};
    G.m10rr = f2{e2.x, e2.y}; G.m10ni = f2{e2.z, e2.w};
    G.m11rr = f2{e3.x, e3.y}; G.m11ni = f2{e3.z, e3.w};
    return G;
}
__device__ __forceinline__ void pin_gate(GateM& G) {
    pin2(G.m00rr); pin2(G.m00ni); pin2(G.m01rr); pin2(G.m01ni);
    pin2(G.m10rr); pin2(G.m10ni); pin2(G.m11rr); pin2(G.m11ni);
}

template<int STRIDE>
__device__ __forceinline__ void apply_gate(f2* s, const GateM G) {
    #pragma unroll
    for (int m0 = 0; m0 < 16; ++m0) {
        if (m0 & STRIDE) continue;
        const int m1 = m0 | STRIDE;
        const f2 a = s[m0], b = s[m1];
        const f2 as = swap2(a), bs = swap2(b);
        f2 o0 = G.m00rr * a;
        o0 = pkfma(G.m00ni, as, o0);
        o0 = pkfma(G.m01rr, b,  o0);
        o0 = pkfma(G.m01ni, bs, o0);
        f2 o1 = G.m10rr * a;
        o1 = pkfma(G.m10ni, as, o1);
        o1 = pkfma(G.m11rr, b,  o1);
        o1 = pkfma(G.m11ni, bs, o1);
        s[m0] = o0; s[m1] = o1;
    }
}

template<int BC, int BT>
__device__ __forceinline__ void apply_cnot(f2* s) {
    #pragma unroll
    for (int m = 0; m < 16; ++m) {
        if ((m & BC) && !(m & BT)) {
            const int m2 = m | BT;
            const f2 t = s[m]; s[m] = s[m2]; s[m2] = t;
        }
    }
}

struct Node { f2 cc, ss, ns; };

__device__ __forceinline__ Node node_cs(float lo, float hi) {
    const float den = lo + hi;
    const bool ok = den > 1e-30f;
    const float rs = __builtin_amdgcn_rsqf(fmaxf(den, 1e-37f));
    const float c = ok ? __builtin_amdgcn_sqrtf(lo) * rs : 1.0f;
    const float s = ok ? __builtin_amdgcn_sqrtf(hi) * rs : 0.0f;
    return Node{f2{c, c}, f2{s, s}, f2{-s, -s}};
}

template<int I0, int I1>
__device__ __forceinline__ void rot_pair(f2* s, const Node& n) {
    const f2 a = s[I0], b = s[I1];
    s[I0] = pkfma(n.cc, a, n.ns * b);
    s[I1] = pkfma(n.ss, a, n.cc * b);
}

__device__ __forceinline__ void cascade(f2* s, const float* Q) {
    const float s01 = Q[0]+Q[1], s23 = Q[2]+Q[3];
    const float s45 = Q[4]+Q[5], s67 = Q[6]+Q[7];
    const float s03 = s01+s23, s47 = s45+s67, s07 = s03+s47;
    const Node n0  = node_cs(s07,  Q[8]);
    const Node n1  = node_cs(s03,  s47);
    const Node n2a = node_cs(s01,  s23);
    const Node n2b = node_cs(s45,  s67);
    const Node n3a = node_cs(Q[0], Q[1]);
    const Node n3b = node_cs(Q[2], Q[3]);
    const Node n3c = node_cs(Q[4], Q[5]);
    const Node n3d = node_cs(Q[6], Q[7]);

    rot_pair<0, 8>(s, n0);  rot_pair<1, 9>(s, n0);
    rot_pair<2,10>(s, n0);  rot_pair<3,11>(s, n0);
    rot_pair<4,12>(s, n0);  rot_pair<5,13>(s, n0);
    rot_pair<6,14>(s, n0);  rot_pair<7,15>(s, n0);
    rot_pair<0, 4>(s, n1);  rot_pair<1, 5>(s, n1);
    rot_pair<2, 6>(s, n1);  rot_pair<3, 7>(s, n1);
    rot_pair<0, 2>(s, n2a); rot_pair<1, 3>(s, n2a);
    rot_pair<4, 6>(s, n2b); rot_pair<5, 7>(s, n2b);
    rot_pair<0, 1>(s, n3a); rot_pair<2, 3>(s, n3b);
    rot_pair<4, 5>(s, n3c); rot_pair<6, 7>(s, n3d);
}

__device__ __forceinline__ void gate_block(f2* s, const GateM* g) {
    apply_gate<4>(s, g[1]);
    apply_gate<2>(s, g[2]);
    apply_gate<1>(s, g[3]);
    apply_cnot<8, 4>(s); apply_cnot<4, 2>(s);
    apply_cnot<2, 1>(s); apply_cnot<1, 8>(s);
    apply_gate<8>(s, g[4]);
    apply_gate<4>(s, g[5]);
    apply_gate<2>(s, g[6]);
    apply_gate<1>(s, g[7]);
    apply_cnot<8, 2>(s); apply_cnot<4, 1>(s);
    apply_cnot<2, 8>(s); apply_cnot<1, 4>(s);
}

// One channel: batched LDS prefetch (patches first, then gates), pin, compute.
template<int IC, bool FIRST>
__device__ __forceinline__ void do_channel(f2* s, const float* smat,
        const float* tile, int ly, int colm, int xc, int colp,
        bool inm, bool inp) {
    // ---- issue patch loads (return first) ----
    float p[9];
    #pragma unroll
    for (int dy = 0; dy < 3; ++dy) {
        const float* row = tile + ((ly + dy) * 4 + IC) * 64;
        p[dy*3 + 0] = row[colm];
        p[dy*3 + 1] = row[xc];
        p[dy*3 + 2] = row[colp];
    }
    // ---- issue gate loads (stay in flight under the cascade) ----
    GateM g[8];
    const float* cb = smat + IC * 128;
    #pragma unroll
    for (int i = 0; i < 8; ++i) g[i] = load_gate(cb + i * 16);

    // ---- pin patches (waits only for the 9 patch reads) ----
    #pragma unroll
    for (int j = 0; j < 9; ++j) pinf(p[j]);

    float q[9];
    #pragma unroll
    for (int dy = 0; dy < 3; ++dy) {
        float vm = inm ? p[dy*3 + 0] : 0.01f;
        float v0 = p[dy*3 + 1];
        float vp = inp ? p[dy*3 + 2] : 0.01f;
        q[dy*3 + 0] = vm * vm;
        q[dy*3 + 1] = v0 * v0;
        q[dy*3 + 2] = vp * vp;
    }

    if constexpr (FIRST) {
        // Mottonen on |0>: state = amplitudes (real). Then g[0] on a real,
        // 9-sparse state defines all of s[].
        const float S = ((q[0]+q[1]) + (q[2]+q[3])) +
                        ((q[4]+q[5]) + (q[6]+q[7])) + q[8];
        const bool ok = S > 1e-30f;
        const float rs = __builtin_amdgcn_rsqf(fmaxf(S, 1e-37f));
        float ar[9];
        #pragma unroll
        for (int j = 0; j < 9; ++j) {
            const float a = __builtin_amdgcn_sqrtf(q[j]) * rs;
            ar[j] = ok ? a : (j == 0 ? 1.0f : 0.0f);
        }
        #pragma unroll
        for (int i = 0; i < 8; ++i) pin_gate(g[i]);
        const f2 m00 = f2{g[0].m00rr.x, g[0].m00ni.y};
        const f2 m01 = f2{g[0].m01rr.x, g[0].m01ni.y};
        const f2 m10 = f2{g[0].m10rr.x, g[0].m10ni.y};
        const f2 m11 = f2{g[0].m11rr.x, g[0].m11ni.y};
        s[0] = pkfma(f2{ar[8], ar[8]}, m01, f2{ar[0], ar[0]} * m00);
        s[8] = pkfma(f2{ar[8], ar[8]}, m11, f2{ar[0], ar[0]} * m10);
        #pragma unroll
        for (int j = 1; j < 8; ++j) {
            s[j]     = f2{ar[j], ar[j]} * m00;
            s[j + 8] = f2{ar[j], ar[j]} * m10;
        }
    } else {
        cascade(s, q);                    // gate loads still in flight here
        #pragma unroll
        for (int i = 0; i < 8; ++i) pin_gate(g[i]);
        apply_gate<8>(s, g[0]);
    }
    gate_block(s, g);
}

__global__ __launch_bounds__(256) void qconv_kernel(
        const float* __restrict__ x,     // (32, 4, 64, 64)
        const float* __restrict__ wts,   // (4, 2, 4, 3)
        float* __restrict__ out) {       // (32, 16, 64, 64)
    __shared__ float smat[32 * 16];
    __shared__ float tile[6 * 4 * 64];

    const int tid = threadIdx.x;
    const int blk = blockIdx.x;
    const int b  = blk >> 4;
    const int y0 = (blk & 15) << 2;

    // --- issue the 6 tile global loads early ---
    const float* xb = x + (size_t)b * 16384;
    float tv[6];
    int   te[6];
    #pragma unroll
    for (int i = 0; i < 6; ++i) {
        const int e = tid + i * 256;          // [r][ch][col]
        const int r = e >> 8, ch = (e >> 6) & 3, col = e & 63;
        const int gy = y0 - 1 + r;
        const int gyc = min(max(gy, 0), 63);
        tv[i] = xb[ch * 4096 + gyc * 64 + col];
        te[i] = e | (((unsigned)gy < 64u) ? 0 : (1 << 30));
    }

    // --- build packed Rot matrices (overlaps the global loads) ---
    if (tid < 32) {
        const float phi   = wts[tid*3 + 0];
        const float theta = wts[tid*3 + 1];
        const float omega = wts[tid*3 + 2];
        float st, ct; __sincosf(0.5f * theta,         &st, &ct);
        float sA, cA; __sincosf(0.5f * (phi + omega), &sA, &cA);
        float sB, cB; __sincosf(0.5f * (phi - omega), &sB, &cB);
        float* g = &smat[tid * 16];
        g[0]  =  cA*ct; g[1]  =  cA*ct; g[2]  =  sA*ct; g[3]  = -sA*ct; // m00
        g[4]  = -cB*st; g[5]  = -cB*st; g[6]  =  sB*st; g[7]  = -sB*st; // m01
        g[8]  =  cB*st; g[9]  =  cB*st; g[10] =  sB*st; g[11] = -sB*st; // m10
        g[12] =  cA*ct; g[13] =  cA*ct; g[14] = -sA*ct; g[15] =  sA*ct; // m11
    }

    #pragma unroll
    for (int i = 0; i < 6; ++i) {
        const bool oob = (te[i] >> 30) & 1;
        tile[te[i] & 0xFFFF] = oob ? 0.01f : tv[i];
    }
    __syncthreads();

    const int ly = tid >> 6, xc = tid & 63;
    const int colm = min(max(xc - 1, 0), 63);
    const int colp = min(xc + 1, 63);
    const bool inm = xc > 0, inp = xc < 63;

    f2 s[16];
    do_channel<0, true >(s, smat, tile, ly, colm, xc, colp, inm, inp);
    do_channel<1, false>(s, smat, tile, ly, colm, xc, colp, inm, inp);
    do_channel<2, false>(s, smat, tile, ly, colm, xc, colp, inm, inp);
    do_channel<3, false>(s, smat, tile, ly, colm, xc, colp, inm, inp);

    float* ob = out + (size_t)b * (16 * 4096) + (y0 + ly) * 64 + xc;
    #pragma unroll
    for (int m = 0; m < 16; ++m) {
        const float pr = s[m].x * s[m].x + s[m].y * s[m].y;
        ob[m * 4096] = fminf(pr * 8.0f, 1.0f);
    }
}

extern "C" void kernel_launch(void* const* d_in, const int* in_sizes, int n_in,
                              void* d_out, int out_size, void* d_ws, size_t ws_size,
                              hipStream_t stream) {
    const float* x   = (const float*)d_in[0];
    const float* wts = (const float*)d_in[1];
    float* out = (float*)d_out;
    qconv_kernel<<<512, 256, 0, stream>>>(x, wts, out);
}